// Round 3
// baseline (13807.545 us; speedup 1.0000x reference)
//
#include <hip/hip_runtime.h>
#include <hip/hip_bf16.h>
#include <math.h>

// LSTM: S=512, B=32, I=1024, H=1024, L=2
// Persistent cooperative kernel, 256 blocks (1/CU) x 256 threads.
// W resident in LDS (128 KB/CU), c-state in LDS, two-level grid barrier
// between recurrence phases. Layer pipelining: phase p = layer0 step p
// + layer1 step p-1. Each wave owns a K-slice of 512 and computes the
// full 32x32 output tile; wave partials reduced via LDS.

typedef short bf16x8 __attribute__((ext_vector_type(8)));
typedef float f32x4 __attribute__((ext_vector_type(4)));
typedef unsigned short u16x8 __attribute__((ext_vector_type(8)));

union ABFrag { bf16x8 v; uint2 u[2]; };

__device__ __forceinline__ unsigned short f2bf(float x){
  unsigned u = __float_as_uint(x);
  u = u + 0x7FFFu + ((u >> 16) & 1u);   // round-to-nearest-even
  return (unsigned short)(u >> 16);
}
__device__ __forceinline__ float sigf(float x){ return 1.0f / (1.0f + __expf(-x)); }
__device__ __forceinline__ float tanhfast(float x){
  float e = __expf(2.0f * x);
  return 1.0f - 2.0f / (e + 1.0f);      // safe at +/-inf
}

// ---- x (f32) -> bf16, [512][32][1024], 8 elems/thread ----
__global__ void k_conv_x(const float* __restrict__ x, u16x8* __restrict__ xb){
  int i = blockIdx.x * blockDim.x + threadIdx.x;   // 2,097,152 threads
  const float4* xf = (const float4*)x;
  float4 a = xf[i * 2];
  float4 c = xf[i * 2 + 1];
  u16x8 o = { f2bf(a.x), f2bf(a.y), f2bf(a.z), f2bf(a.w),
              f2bf(c.x), f2bf(c.y), f2bf(c.z), f2bf(c.w) };
  xb[i] = o;
}

// ---- pack W (f32) -> per-block bf16 MFMA B-fragment slabs ----
// wp[blk(256)][ct(2)][kt(64)][lane(64)] : 16B frag. blk = layer*128 + hb/8.
// MFMA-tile column col32 = ct*16 + (lane&15) maps to weight column
// (col32&3)*1024 + hb + (col32>>2)  -> gates interleaved so the z-reduce
// reads {f,g,i,o} of one hidden unit as a single f32x4.
// k map (must match A side): k = kt*32 + (lane>>4)*4 + (i&3) + 16*(i>>2)
__global__ void k_pack_w(const float* __restrict__ W, u16x8* __restrict__ wp){
  int t = blockIdx.x * blockDim.x + threadIdx.x;   // 2,097,152 threads
  int lane = t & 63;
  int kt   = (t >> 6) & 63;
  int ct   = (t >> 12) & 1;
  int blk  = t >> 13;
  int layer = blk >> 7;
  int hb = (blk & 127) * 8;
  int lm = lane & 15, lk = lane >> 4;
  int col32 = ct * 16 + lm;
  int col = (col32 & 3) * 1024 + hb + (col32 >> 2);
  int kb = kt * 32 + lk * 4;
  const float* Wl = W + (size_t)layer * 2048 * 4096;
  u16x8 o;
  #pragma unroll
  for (int i = 0; i < 8; ++i){
    int k = kb + (i & 3) + ((i >> 2) << 4);
    o[i] = f2bf(Wl[(size_t)k * 4096 + col]);
  }
  wp[t] = o;
}

// ---- two-level device-scope grid barrier ----
// gcnt: 8 group counters, 128 B apart (32 blocks/group). root: 8 adds/phase.
// Monotonic targets -> no reset needed. ph = 1,2,3,...
__device__ __forceinline__ void gridbar2(unsigned* gcnt, unsigned* root, unsigned ph){
  __syncthreads();
  if (threadIdx.x == 0) {
    __threadfence();                     // publish this block's global stores
    unsigned* gc = gcnt + ((blockIdx.x >> 5) << 5);
    unsigned old = __hip_atomic_fetch_add(gc, 1u, __ATOMIC_ACQ_REL, __HIP_MEMORY_SCOPE_AGENT);
    if (old == ph * 32u - 1u)            // last arriver of this group
      __hip_atomic_fetch_add(root, 1u, __ATOMIC_ACQ_REL, __HIP_MEMORY_SCOPE_AGENT);
    while (__hip_atomic_load(root, __ATOMIC_ACQUIRE, __HIP_MEMORY_SCOPE_AGENT) < ph * 8u)
      __builtin_amdgcn_s_sleep(1);
  }
  __syncthreads();
}

// ---- the persistent kernel ----
__global__ __launch_bounds__(256) void lstm_coop(
    const unsigned short* __restrict__ xbf,
    const uint4* __restrict__ wpack,
    const float* __restrict__ h0,
    const float* __restrict__ c0,
    const float* __restrict__ bias,
    unsigned short* __restrict__ h1pp,   // [2][32][1024] bf16 ping-pong
    unsigned short* __restrict__ h2pp,   // [2][32][1024] bf16 ping-pong
    float* __restrict__ out,
    unsigned* __restrict__ gcnt,
    unsigned* __restrict__ root)
{
  extern __shared__ char smem[];
  uint4* wl = (uint4*)smem;                         // 131072 B : W fragments
  float* zl = (float*)(smem + 131072);              //  18432 B : z[4][32][36]
  float* cl = (float*)(smem + 131072 + 18432);      //   1024 B : c[32][8]

  const int bid = blockIdx.x;
  const int layer = bid >> 7;
  const int hb = (bid & 127) * 8;
  const int tid = threadIdx.x;
  const int w = tid >> 6, l = tid & 63, lm = l & 15, lk = l >> 4;
  const int row = tid >> 3, jj = tid & 7, col = hb + jj;

  // ---- prologue: W -> LDS (one-time), states, bias regs ----
  const uint4* wsrc = wpack + (size_t)bid * 8192;
  #pragma unroll 4
  for (int i = tid; i < 8192; i += 256) wl[i] = wsrc[i];

  cl[tid] = c0[layer * 32768 + row * 1024 + col];
  float h0v = h0[layer * 32768 + row * 1024 + col];
  (layer ? h2pp : h1pp)[32768 + row * 1024 + col] = f2bf(h0v);  // slot 1 = state(t=-1)

  const float* bl = bias + layer * 4096;
  const float bF = bl[col], bG = bl[1024 + col], bI = bl[2048 + col], bO = bl[3072 + col];

  unsigned bar = 0;
  gridbar2(gcnt, root, ++bar);                      // init + W visible

  // wave w: K-slice [w*512, (w+1)*512). Waves 0,1 read first source
  // (x or h1(t)), waves 2,3 read second (h-recurrent).
  const uint4* bw = wl + (w * 16) * 64 + l;         // B frags, ct stride 4096
  const int aoff = lm * 1024 + (w & 1) * 512 + lk * 4;
  float* zw = zl + w * 1152;

  for (int p = 0; p <= 512; ++p) {
    const bool active = layer ? (p >= 1) : (p < 512);
    if (active) {
      const int t = layer ? (p - 1) : p;
      const unsigned short *srcA, *srcB;
      unsigned short* hdst;
      if (layer == 0) {
        srcA = xbf + (size_t)p * 32768;             // x(t)
        srcB = h1pp + ((p + 1) & 1) * 32768;        // h1(t-1)
        hdst = h1pp + (p & 1) * 32768;              // h1(t)
      } else {
        srcA = h1pp + ((p + 1) & 1) * 32768;        // h1(t)   (written phase p-1)
        srcB = h2pp + (p & 1) * 32768;              // h2(t-1) (written phase p-1)
        hdst = h2pp + ((p + 1) & 1) * 32768;        // h2(t)
      }
      const unsigned short* s0 = ((w < 2) ? srcA : srcB) + aoff;  // rows 0-15
      const unsigned short* s1 = s0 + 16 * 1024;                  // rows 16-31

      f32x4 a00 = {0,0,0,0}, a01 = {0,0,0,0}, a10 = {0,0,0,0}, a11 = {0,0,0,0};
      #pragma unroll
      for (int ktl = 0; ktl < 16; ++ktl) {
        ABFrag A0, A1;
        A0.u[0] = *(const uint2*)(s0 + ktl * 32);
        A0.u[1] = *(const uint2*)(s0 + ktl * 32 + 16);
        A1.u[0] = *(const uint2*)(s1 + ktl * 32);
        A1.u[1] = *(const uint2*)(s1 + ktl * 32 + 16);
        uint4 b0 = bw[ktl * 64];
        uint4 b1 = bw[4096 + ktl * 64];
        a00 = __builtin_amdgcn_mfma_f32_16x16x32_bf16(A0.v, *(const bf16x8*)&b0, a00, 0, 0, 0);
        a10 = __builtin_amdgcn_mfma_f32_16x16x32_bf16(A1.v, *(const bf16x8*)&b0, a10, 0, 0, 0);
        a01 = __builtin_amdgcn_mfma_f32_16x16x32_bf16(A0.v, *(const bf16x8*)&b1, a01, 0, 0, 0);
        a11 = __builtin_amdgcn_mfma_f32_16x16x32_bf16(A1.v, *(const bf16x8*)&b1, a11, 0, 0, 0);
      }

      // partials -> LDS. C/D layout: col=lane&15, row=(lane>>4)*4+reg.
      // row stride 36 floats -> write banks 2-way (free), read b128 uniform.
      #pragma unroll
      for (int r = 0; r < 4; ++r) {
        zw[(lk * 4 + r) * 36 + lm]           = a00[r];
        zw[(lk * 4 + r) * 36 + 16 + lm]      = a01[r];
        zw[(16 + lk * 4 + r) * 36 + lm]      = a10[r];
        zw[(16 + lk * 4 + r) * 36 + 16 + lm] = a11[r];
      }
      __syncthreads();

      // reduce 4 wave-partials; col32 = jj*4+gate -> one b128 per part
      const int zo_ = row * 36 + jj * 4;
      f32x4 z0 = *(const f32x4*)&zl[zo_];
      f32x4 z1 = *(const f32x4*)&zl[1152 + zo_];
      f32x4 z2 = *(const f32x4*)&zl[2304 + zo_];
      f32x4 z3 = *(const f32x4*)&zl[3456 + zo_];
      f32x4 zz = (z0 + z1) + (z2 + z3);

      float fg = sigf(zz[0] + bF);
      float gg = tanhfast(zz[1] + bG);
      float ig = sigf(sigf(zz[2] + bI));              // faithful double-sigmoid quirk
      float og = sigf(zz[3] + bO);
      float cn = cl[tid] * fg + gg * ig;
      float hn = og * tanhfast(cn);
      cl[tid] = cn;
      hdst[row * 1024 + col] = f2bf(hn);
      if (layer) out[(size_t)t * 32768 + row * 1024 + col] = hn;
      if (t == 511) {
        out[16777216 + layer * 32768 + row * 1024 + col] = hn;   // h_fin
        out[16842752 + layer * 32768 + row * 1024 + col] = cn;   // c_fin
      }
    }
    if (p < 512) gridbar2(gcnt, root, ++bar);
  }
}

extern "C" void kernel_launch(void* const* d_in, const int* in_sizes, int n_in,
                              void* d_out, int out_size, void* d_ws, size_t ws_size,
                              hipStream_t stream)
{
  (void)in_sizes; (void)n_in; (void)out_size; (void)ws_size;
  const float* x  = (const float*)d_in[0];
  const float* h0 = (const float*)d_in[1];
  const float* c0 = (const float*)d_in[2];
  const float* W  = (const float*)d_in[3];
  const float* b  = (const float*)d_in[4];
  float* out = (float*)d_out;

  char* ws = (char*)d_ws;
  u16x8*          xbf_v = (u16x8*)ws;                        //  0    : 32 MB
  u16x8*          wp_v  = (u16x8*)(ws + 33554432);           // 32 MB : 32 MB
  unsigned short* h1pp  = (unsigned short*)(ws + 67108864);  // 128 KB
  unsigned short* h2pp  = (unsigned short*)(ws + 67239936);  // 128 KB
  unsigned*       gcnt  = (unsigned*)(ws + 67371008);        // 8 x 128 B
  unsigned*       root  = (unsigned*)(ws + 67372032);        // 128 B

  hipMemsetAsync(gcnt, 0, 2048, stream);                     // zero gcnt + root
  k_conv_x<<<8192, 256, 0, stream>>>(x, xbf_v);
  k_pack_w<<<8192, 256, 0, stream>>>(W, wp_v);

  size_t shmem = 131072 + 18432 + 1024;   // 150528 B < 160 KiB
  hipFuncSetAttribute((const void*)lstm_coop,
                      hipFuncAttributeMaxDynamicSharedMemorySize, (int)(160 * 1024));

  const unsigned short* xbf_p = (const unsigned short*)xbf_v;
  const uint4*          wp_p  = (const uint4*)wp_v;
  void* args[] = {
    (void*)&xbf_p, (void*)&wp_p, (void*)&h0, (void*)&c0, (void*)&b,
    (void*)&h1pp, (void*)&h2pp, (void*)&out, (void*)&gcnt, (void*)&root
  };
  hipLaunchCooperativeKernel((const void*)lstm_coop, dim3(256), dim3(256),
                             args, (unsigned)shmem, stream);
}

// Round 5
// 8566.870 us; speedup vs baseline: 1.6117x; 1.6117x over previous
//
#include <hip/hip_runtime.h>
#include <hip/hip_bf16.h>
#include <math.h>

// LSTM: S=512, B=32, I=1024, H=1024, L=2
// Persistent cooperative kernel, 256 blocks (1/CU) x 256 threads.
// W resident in LDS (128 KB/CU), c-state in LDS. Layer pipelining:
// phase p = layer0 step p + layer1 step p-1.
// Barrier v2: one wbl2 (release-add) + relaxed spin + one buffer_inv
// (acquire fence) per block per phase. h histories are ROLLING (each
// slot written once) so no ping-pong anti-dependencies.

typedef short bf16x8 __attribute__((ext_vector_type(8)));
typedef float f32x4 __attribute__((ext_vector_type(4)));
typedef unsigned short u16x8 __attribute__((ext_vector_type(8)));

union ABFrag { bf16x8 v; uint2 u[2]; };

__device__ __forceinline__ unsigned short f2bf(float x){
  unsigned u = __float_as_uint(x);
  u = u + 0x7FFFu + ((u >> 16) & 1u);   // round-to-nearest-even
  return (unsigned short)(u >> 16);
}
__device__ __forceinline__ float sigf(float x){ return 1.0f / (1.0f + __expf(-x)); }
__device__ __forceinline__ float tanhfast(float x){
  float e = __expf(2.0f * x);
  return 1.0f - 2.0f / (e + 1.0f);      // safe at +/-inf
}

// ---- x (f32) -> bf16, [512][32][1024], 8 elems/thread ----
__global__ void k_conv_x(const float* __restrict__ x, u16x8* __restrict__ xb){
  int i = blockIdx.x * blockDim.x + threadIdx.x;   // 2,097,152 threads
  const float4* xf = (const float4*)x;
  float4 a = xf[i * 2];
  float4 c = xf[i * 2 + 1];
  u16x8 o = { f2bf(a.x), f2bf(a.y), f2bf(a.z), f2bf(a.w),
              f2bf(c.x), f2bf(c.y), f2bf(c.z), f2bf(c.w) };
  xb[i] = o;
}

// ---- pack W (f32) -> per-block bf16 MFMA B-fragment slabs ----
// wp[blk(256)][ct(2)][kt(64)][lane(64)] : 16B frag. blk = layer*128 + hb/8.
// MFMA-tile column col32 = ct*16 + (lane&15) -> weight column
// (col32&3)*1024 + hb + (col32>>2)  (gates interleaved: z-reduce reads
// {f,g,i,o} of one hidden unit as one f32x4).
// k map (must match A side): k = kt*32 + (lane>>4)*4 + (i&3) + 16*(i>>2)
__global__ void k_pack_w(const float* __restrict__ W, u16x8* __restrict__ wp){
  int t = blockIdx.x * blockDim.x + threadIdx.x;   // 2,097,152 threads
  int lane = t & 63;
  int kt   = (t >> 6) & 63;
  int ct   = (t >> 12) & 1;
  int blk  = t >> 13;
  int layer = blk >> 7;
  int hb = (blk & 127) * 8;
  int lm = lane & 15, lk = lane >> 4;
  int col32 = ct * 16 + lm;
  int col = (col32 & 3) * 1024 + hb + (col32 >> 2);
  int kb = kt * 32 + lk * 4;
  const float* Wl = W + (size_t)layer * 2048 * 4096;
  u16x8 o;
  #pragma unroll
  for (int i = 0; i < 8; ++i){
    int k = kb + (i & 3) + ((i >> 2) << 4);
    o[i] = f2bf(Wl[(size_t)k * 4096 + col]);
  }
  wp[t] = o;
}

// ---- two-level grid barrier, minimal cache-maintenance ----
// arrive: syncthreads (drains vmcnt) + ONE release fetch_add (one wbl2).
// Last of each 32-group bumps root with RELEASE (carries the group's
// release chain; +1 wbl2 for 8 leaders only).
__device__ __forceinline__ void bar_arrive(unsigned* gcnt, unsigned* root, unsigned ph){
  __syncthreads();
  if (threadIdx.x == 0) {
    unsigned* gc = gcnt + ((blockIdx.x >> 5) << 5);   // 8 groups, 128 B apart
    unsigned old = __hip_atomic_fetch_add(gc, 1u, __ATOMIC_RELEASE, __HIP_MEMORY_SCOPE_AGENT);
    if (old == ph * 32u - 1u)
      __hip_atomic_fetch_add(root, 1u, __ATOMIC_RELEASE, __HIP_MEMORY_SCOPE_AGENT);
  }
}
// wait: RELAXED spin (load at coherence point, NO per-iteration
// invalidate), then ONE acquire fence (one buffer_inv).
__device__ __forceinline__ void bar_wait(unsigned* root, unsigned ph){
  if (threadIdx.x == 0) {
    while (__hip_atomic_load(root, __ATOMIC_RELAXED, __HIP_MEMORY_SCOPE_AGENT) < ph * 8u)
      __builtin_amdgcn_s_sleep(4);
    __builtin_amdgcn_fence(__ATOMIC_ACQUIRE, "agent");
  }
  __syncthreads();
}

// ---- the persistent kernel ----
__global__ __launch_bounds__(256) void lstm_coop(
    const unsigned short* __restrict__ xbf,
    const uint4* __restrict__ wpack,
    const float* __restrict__ h0,
    const float* __restrict__ c0,
    const float* __restrict__ bias,
    unsigned short* __restrict__ h1x,    // [513][32][1024] bf16 rolling history
    unsigned short* __restrict__ h2x,    // [513][32][1024] bf16 rolling history
    float* __restrict__ out,
    unsigned* __restrict__ gcnt,
    unsigned* __restrict__ root)
{
  extern __shared__ char smem[];
  uint4* wl = (uint4*)smem;                         // 131072 B : W fragments
  float* zl = (float*)(smem + 131072);              //  18432 B : z[4][32][36]
  float* cl = (float*)(smem + 131072 + 18432);      //   1024 B : c[32][8]

  const int bid = blockIdx.x;
  const int layer = bid >> 7;
  const int hb = (bid & 127) * 8;
  const int tid = threadIdx.x;
  const int w = tid >> 6, l = tid & 63, lm = l & 15, lk = l >> 4;
  const int row = tid >> 3, jj = tid & 7, col = hb + jj;

  // ---- prologue: W -> LDS (one-time), states, bias regs ----
  const uint4* wsrc = wpack + (size_t)bid * 8192;
  #pragma unroll 4
  for (int i = tid; i < 8192; i += 256) wl[i] = wsrc[i];

  cl[tid] = c0[layer * 32768 + row * 1024 + col];
  float h0v = h0[layer * 32768 + row * 1024 + col];
  (layer ? h2x : h1x)[row * 1024 + col] = f2bf(h0v);   // slot 0 = state(t=-1)

  const float* bl = bias + layer * 4096;
  const float bF = bl[col], bG = bl[1024 + col], bI = bl[2048 + col], bO = bl[3072 + col];

  bar_arrive(gcnt, root, 1);
  bar_wait(root, 1);

  // wave w: K-slice [w*512,(w+1)*512). Waves 0,1 read srcA, waves 2,3 srcB.
  const uint4* bw = wl + (w * 16) * 64 + l;         // B frags, ct stride 4096
  const int aoff = lm * 1024 + (w & 1) * 512 + lk * 4;
  float* zw = zl + w * 1152;

  for (int p = 0; p <= 512; ++p) {
    const bool active = layer ? (p >= 1) : (p < 512);
    const int t = layer ? (p - 1) : p;
    float hn = 0.f, cn = 0.f;
    if (active) {
      const unsigned short *srcA, *srcB;
      unsigned short* hdst;
      if (layer == 0) {
        srcA = xbf + (size_t)p * 32768;             // x(t)
        srcB = h1x + (size_t)p * 32768;             // h1(t-1) = slot p
        hdst = h1x + (size_t)(p + 1) * 32768;       // h1(t)   = slot p+1
      } else {
        srcA = h1x + (size_t)p * 32768;             // h1(t)   (written phase p-1)
        srcB = h2x + (size_t)(p - 1) * 32768;       // h2(t-1) = slot p-1
        hdst = h2x + (size_t)p * 32768;             // h2(t)   = slot p
      }
      const unsigned short* s0 = ((w < 2) ? srcA : srcB) + aoff;  // rows 0-15
      const unsigned short* s1 = s0 + 16 * 1024;                  // rows 16-31

      f32x4 a00 = {0,0,0,0}, a01 = {0,0,0,0}, a10 = {0,0,0,0}, a11 = {0,0,0,0};
      #pragma unroll
      for (int ktl = 0; ktl < 16; ++ktl) {
        ABFrag A0, A1;
        A0.u[0] = *(const uint2*)(s0 + ktl * 32);
        A0.u[1] = *(const uint2*)(s0 + ktl * 32 + 16);
        A1.u[0] = *(const uint2*)(s1 + ktl * 32);
        A1.u[1] = *(const uint2*)(s1 + ktl * 32 + 16);
        uint4 b0 = bw[ktl * 64];
        uint4 b1 = bw[4096 + ktl * 64];
        a00 = __builtin_amdgcn_mfma_f32_16x16x32_bf16(A0.v, *(const bf16x8*)&b0, a00, 0, 0, 0);
        a10 = __builtin_amdgcn_mfma_f32_16x16x32_bf16(A1.v, *(const bf16x8*)&b0, a10, 0, 0, 0);
        a01 = __builtin_amdgcn_mfma_f32_16x16x32_bf16(A0.v, *(const bf16x8*)&b1, a01, 0, 0, 0);
        a11 = __builtin_amdgcn_mfma_f32_16x16x32_bf16(A1.v, *(const bf16x8*)&b1, a11, 0, 0, 0);
      }

      // partials -> LDS (C/D: col=lane&15, row=(lane>>4)*4+reg); row stride 36
      #pragma unroll
      for (int r = 0; r < 4; ++r) {
        zw[(lk * 4 + r) * 36 + lm]           = a00[r];
        zw[(lk * 4 + r) * 36 + 16 + lm]      = a01[r];
        zw[(16 + lk * 4 + r) * 36 + lm]      = a10[r];
        zw[(16 + lk * 4 + r) * 36 + 16 + lm] = a11[r];
      }
      __syncthreads();

      // reduce 4 wave-partials; col32 = jj*4+gate -> one b128 per part
      const int zo_ = row * 36 + jj * 4;
      f32x4 z0 = *(const f32x4*)&zl[zo_];
      f32x4 z1 = *(const f32x4*)&zl[1152 + zo_];
      f32x4 z2 = *(const f32x4*)&zl[2304 + zo_];
      f32x4 z3 = *(const f32x4*)&zl[3456 + zo_];
      f32x4 zz = (z0 + z1) + (z2 + z3);

      float fg = sigf(zz[0] + bF);
      float gg = tanhfast(zz[1] + bG);
      float ig = sigf(sigf(zz[2] + bI));              // faithful double-sigmoid quirk
      float og = sigf(zz[3] + bO);
      cn = cl[tid] * fg + gg * ig;
      hn = og * tanhfast(cn);
      cl[tid] = cn;
      hdst[row * 1024 + col] = f2bf(hn);              // cross-block data: before arrive
    }
    if (p < 512) {
      bar_arrive(gcnt, root, (unsigned)(p + 2));
      // private out-stores overlap the spin (nobody reads these in-kernel)
      if (active && layer) out[(size_t)t * 32768 + row * 1024 + col] = hn;
      if (active && t == 511) {
        out[16777216 + layer * 32768 + row * 1024 + col] = hn;   // h_fin
        out[16842752 + layer * 32768 + row * 1024 + col] = cn;   // c_fin
      }
      bar_wait(root, (unsigned)(p + 2));
    } else {
      if (active && layer) out[(size_t)t * 32768 + row * 1024 + col] = hn;
      if (active && t == 511) {
        out[16777216 + layer * 32768 + row * 1024 + col] = hn;
        out[16842752 + layer * 32768 + row * 1024 + col] = cn;
      }
    }
  }
}

extern "C" void kernel_launch(void* const* d_in, const int* in_sizes, int n_in,
                              void* d_out, int out_size, void* d_ws, size_t ws_size,
                              hipStream_t stream)
{
  (void)in_sizes; (void)n_in; (void)out_size; (void)ws_size;
  const float* x  = (const float*)d_in[0];
  const float* h0 = (const float*)d_in[1];
  const float* c0 = (const float*)d_in[2];
  const float* W  = (const float*)d_in[3];
  const float* b  = (const float*)d_in[4];
  float* out = (float*)d_out;

  char* ws = (char*)d_ws;
  u16x8*          xbf_v = (u16x8*)ws;                         //   0       : 32 MB
  u16x8*          wp_v  = (u16x8*)(ws + 33554432);            //  32 MB    : 32 MB
  unsigned short* h1x   = (unsigned short*)(ws + 67108864);   //  64 MB    : 513*64 KB
  unsigned short* h2x   = (unsigned short*)(ws + 100728832);  //  ~96 MB   : 513*64 KB
  unsigned*       gcnt  = (unsigned*)(ws + 134348800);        // 8 x 128 B
  unsigned*       root  = (unsigned*)(ws + 134349824);        // 128 B
  // total ~134.4 MB of ws

  hipMemsetAsync(gcnt, 0, 2048, stream);                      // gcnt + root
  k_conv_x<<<8192, 256, 0, stream>>>(x, xbf_v);
  k_pack_w<<<8192, 256, 0, stream>>>(W, wp_v);

  size_t shmem = 131072 + 18432 + 1024;   // 150528 B < 160 KiB
  hipFuncSetAttribute((const void*)lstm_coop,
                      hipFuncAttributeMaxDynamicSharedMemorySize, (int)(160 * 1024));

  const unsigned short* xbf_p = (const unsigned short*)xbf_v;
  const uint4*          wp_p  = (const uint4*)wp_v;
  void* args[] = {
    (void*)&xbf_p, (void*)&wp_p, (void*)&h0, (void*)&c0, (void*)&b,
    (void*)&h1x, (void*)&h2x, (void*)&out, (void*)&gcnt, (void*)&root
  };
  hipLaunchCooperativeKernel((const void*)lstm_coop, dim3(256), dim3(256),
                             args, (unsigned)shmem, stream);
}

// Round 7
// 6469.703 us; speedup vs baseline: 2.1342x; 1.3242x over previous
//
#include <hip/hip_runtime.h>
#include <hip/hip_bf16.h>
#include <math.h>

// LSTM: S=512, B=32, I=1024, H=1024, L=2
// Persistent cooperative kernel, 256 blocks (1/CU) x 256 threads.
// W resident in LDS (128 KB/CU), c-state in LDS. Layer pipelining:
// phase p = layer0 step p + layer1 step p-1.
// Sync v3: ZERO cache-maintenance ops. Cross-block h-tiles are written
// with agent-scope relaxed atomic stores (sc1 write-through to the
// coherence point); h histories are rolling (write-once slots) so
// consumer caches can only take compulsory misses -> normal cached
// loads are safe with NO acquire-invalidate. Barrier = vmcnt drain +
// relaxed fetch-add tree (16x16 + root) + relaxed spin.

typedef short bf16x8 __attribute__((ext_vector_type(8)));
typedef float f32x4 __attribute__((ext_vector_type(4)));
typedef unsigned short u16x8 __attribute__((ext_vector_type(8)));

union ABFrag { bf16x8 v; uint2 u[2]; };

__device__ __forceinline__ unsigned short f2bf(float x){
  unsigned u = __float_as_uint(x);
  u = u + 0x7FFFu + ((u >> 16) & 1u);   // round-to-nearest-even
  return (unsigned short)(u >> 16);
}
__device__ __forceinline__ float sigf(float x){ return 1.0f / (1.0f + __expf(-x)); }
__device__ __forceinline__ float tanhfast(float x){
  float e = __expf(2.0f * x);
  return 1.0f - 2.0f / (e + 1.0f);      // safe at +/-inf
}

// ---- x (f32) -> bf16, [512][32][1024], 8 elems/thread ----
__global__ void k_conv_x(const float* __restrict__ x, u16x8* __restrict__ xb){
  int i = blockIdx.x * blockDim.x + threadIdx.x;   // 2,097,152 threads
  const float4* xf = (const float4*)x;
  float4 a = xf[i * 2];
  float4 c = xf[i * 2 + 1];
  u16x8 o = { f2bf(a.x), f2bf(a.y), f2bf(a.z), f2bf(a.w),
              f2bf(c.x), f2bf(c.y), f2bf(c.z), f2bf(c.w) };
  xb[i] = o;
}

// ---- pack W (f32) -> per-block bf16 MFMA B-fragment slabs ----
// wp[blk(256)][ct(2)][kt(64)][lane(64)] : 16B frag. blk = layer*128 + hb/8.
// MFMA-tile column col32 = ct*16 + (lane&15) -> weight column
// (col32&3)*1024 + hb + (col32>>2)  (gates interleaved: z-reduce reads
// {f,g,i,o} of one hidden unit as one f32x4).
// k map (must match A side): k = kt*32 + (lane>>4)*4 + (i&3) + 16*(i>>2)
__global__ void k_pack_w(const float* __restrict__ W, u16x8* __restrict__ wp){
  int t = blockIdx.x * blockDim.x + threadIdx.x;   // 2,097,152 threads
  int lane = t & 63;
  int kt   = (t >> 6) & 63;
  int ct   = (t >> 12) & 1;
  int blk  = t >> 13;
  int layer = blk >> 7;
  int hb = (blk & 127) * 8;
  int lm = lane & 15, lk = lane >> 4;
  int col32 = ct * 16 + lm;
  int col = (col32 & 3) * 1024 + hb + (col32 >> 2);
  int kb = kt * 32 + lk * 4;
  const float* Wl = W + (size_t)layer * 2048 * 4096;
  u16x8 o;
  #pragma unroll
  for (int i = 0; i < 8; ++i){
    int k = kb + (i & 3) + ((i >> 2) << 4);
    o[i] = f2bf(Wl[(size_t)k * 4096 + col]);
  }
  wp[t] = o;
}

// ---- barrier v3: no cache maintenance at all ----
// arrive: drain vmcnt (sc1 data stores ack at coherence point) + relaxed
// fetch-add; 16 groups of 16, leaders bump root (relaxed).
__device__ __forceinline__ void bar_arrive(unsigned* gcnt, unsigned* root, unsigned ph){
  asm volatile("s_waitcnt vmcnt(0)" ::: "memory");
  __syncthreads();
  if (threadIdx.x == 0) {
    unsigned* gc = gcnt + (blockIdx.x >> 4) * 32;   // 16 groups, 128 B apart
    unsigned old = __hip_atomic_fetch_add(gc, 1u, __ATOMIC_RELAXED, __HIP_MEMORY_SCOPE_AGENT);
    if (old == ph * 16u - 1u)
      __hip_atomic_fetch_add(root, 1u, __ATOMIC_RELAXED, __HIP_MEMORY_SCOPE_AGENT);
  }
}
// wait: relaxed spin; no acquire fence (rolling buffers -> compulsory miss).
__device__ __forceinline__ void bar_wait(unsigned* root, unsigned ph){
  if (threadIdx.x == 0) {
    while (__hip_atomic_load(root, __ATOMIC_RELAXED, __HIP_MEMORY_SCOPE_AGENT) < ph * 16u)
      __builtin_amdgcn_s_sleep(1);
  }
  __syncthreads();
}

// agent-scope relaxed store: compiles to write-through (coherence point)
__device__ __forceinline__ void st_pair_agent(unsigned* p, unsigned v){
  __hip_atomic_store(p, v, __ATOMIC_RELAXED, __HIP_MEMORY_SCOPE_AGENT);
}

// ---- the persistent kernel ----
__global__ __launch_bounds__(256) void lstm_coop(
    const unsigned short* __restrict__ xbf,
    const uint4* __restrict__ wpack,
    const float* __restrict__ h0,
    const float* __restrict__ c0,
    const float* __restrict__ bias,
    unsigned short* __restrict__ h1x,    // [513][32][1024] bf16 rolling history
    unsigned short* __restrict__ h2x,    // [513][32][1024] bf16 rolling history
    float* __restrict__ out,
    unsigned* __restrict__ gcnt,
    unsigned* __restrict__ root)
{
  extern __shared__ char smem[];
  uint4* wl = (uint4*)smem;                         // 131072 B : W fragments
  float* zl = (float*)(smem + 131072);              //  18432 B : z[4][32][36]
  float* cl = (float*)(smem + 131072 + 18432);      //   1024 B : c[32][8]

  const int bid = blockIdx.x;
  const int layer = bid >> 7;
  const int hb = (bid & 127) * 8;
  const int tid = threadIdx.x;
  const int w = tid >> 6, l = tid & 63, lm = l & 15, lk = l >> 4;
  const int row = tid >> 3, jj = tid & 7, col = hb + jj;

  // ---- prologue: W -> LDS (one-time), states, bias regs ----
  const uint4* wsrc = wpack + (size_t)bid * 8192;
  #pragma unroll 4
  for (int i = tid; i < 8192; i += 256) wl[i] = wsrc[i];

  cl[tid] = c0[layer * 32768 + row * 1024 + col];
  float h0v = h0[layer * 32768 + row * 1024 + col];
  {
    unsigned short hb16 = f2bf(h0v);
    unsigned pair = (unsigned)hb16 | (__shfl_xor((unsigned)hb16, 1) << 16);
    unsigned short* hinit = layer ? h2x : h1x;       // slot 0 = state(t=-1)
    if ((jj & 1) == 0)
      st_pair_agent((unsigned*)(hinit + row * 1024 + hb) + (jj >> 1), pair);
  }

  const float* bl = bias + layer * 4096;
  const float bF = bl[col], bG = bl[1024 + col], bI = bl[2048 + col], bO = bl[3072 + col];

  bar_arrive(gcnt, root, 1);
  bar_wait(root, 1);

  // wave w: K-slice [w*512,(w+1)*512). Waves 0,1 read srcA, waves 2,3 srcB.
  const uint4* bw = wl + (w * 16) * 64 + l;         // B frags, ct stride 4096
  const int aoff = lm * 1024 + (w & 1) * 512 + lk * 4;
  float* zw = zl + w * 1152;

  for (int p = 0; p <= 512; ++p) {
    const bool active = layer ? (p >= 1) : (p < 512);
    const int t = layer ? (p - 1) : p;
    float hn = 0.f, cn = 0.f;
    if (active) {
      const unsigned short *srcA, *srcB;
      unsigned short* hdst;
      if (layer == 0) {
        srcA = xbf + (size_t)p * 32768;             // x(t)
        srcB = h1x + (size_t)p * 32768;             // h1(t-1) = slot p
        hdst = h1x + (size_t)(p + 1) * 32768;       // h1(t)   = slot p+1
      } else {
        srcA = h1x + (size_t)p * 32768;             // h1(t)   (written phase p-1)
        srcB = h2x + (size_t)(p - 1) * 32768;       // h2(t-1) = slot p-1
        hdst = h2x + (size_t)p * 32768;             // h2(t)   = slot p
      }
      const unsigned short* s0 = ((w < 2) ? srcA : srcB) + aoff;  // rows 0-15
      const unsigned short* s1 = s0 + 16 * 1024;                  // rows 16-31

      f32x4 a00 = {0,0,0,0}, a01 = {0,0,0,0}, a10 = {0,0,0,0}, a11 = {0,0,0,0};
      #pragma unroll
      for (int ktl = 0; ktl < 16; ++ktl) {
        ABFrag A0, A1;
        A0.u[0] = *(const uint2*)(s0 + ktl * 32);
        A0.u[1] = *(const uint2*)(s0 + ktl * 32 + 16);
        A1.u[0] = *(const uint2*)(s1 + ktl * 32);
        A1.u[1] = *(const uint2*)(s1 + ktl * 32 + 16);
        uint4 b0 = bw[ktl * 64];
        uint4 b1 = bw[4096 + ktl * 64];
        a00 = __builtin_amdgcn_mfma_f32_16x16x32_bf16(A0.v, *(const bf16x8*)&b0, a00, 0, 0, 0);
        a10 = __builtin_amdgcn_mfma_f32_16x16x32_bf16(A1.v, *(const bf16x8*)&b0, a10, 0, 0, 0);
        a01 = __builtin_amdgcn_mfma_f32_16x16x32_bf16(A0.v, *(const bf16x8*)&b1, a01, 0, 0, 0);
        a11 = __builtin_amdgcn_mfma_f32_16x16x32_bf16(A1.v, *(const bf16x8*)&b1, a11, 0, 0, 0);
      }

      // partials -> LDS (C/D: col=lane&15, row=(lane>>4)*4+reg); row stride 36
      #pragma unroll
      for (int r = 0; r < 4; ++r) {
        zw[(lk * 4 + r) * 36 + lm]           = a00[r];
        zw[(lk * 4 + r) * 36 + 16 + lm]      = a01[r];
        zw[(16 + lk * 4 + r) * 36 + lm]      = a10[r];
        zw[(16 + lk * 4 + r) * 36 + 16 + lm] = a11[r];
      }
      __syncthreads();

      // reduce 4 wave-partials; col32 = jj*4+gate -> one b128 per part
      const int zo_ = row * 36 + jj * 4;
      f32x4 z0 = *(const f32x4*)&zl[zo_];
      f32x4 z1 = *(const f32x4*)&zl[1152 + zo_];
      f32x4 z2 = *(const f32x4*)&zl[2304 + zo_];
      f32x4 z3 = *(const f32x4*)&zl[3456 + zo_];
      f32x4 zz = (z0 + z1) + (z2 + z3);

      float fg = sigf(zz[0] + bF);
      float gg = tanhfast(zz[1] + bG);
      float ig = sigf(sigf(zz[2] + bI));              // faithful double-sigmoid quirk
      float og = sigf(zz[3] + bO);
      cn = cl[tid] * fg + gg * ig;
      hn = og * tanhfast(cn);
      cl[tid] = cn;

      // cross-block h publish: paired 32-bit agent store (write-through)
      {
        unsigned short hb16 = f2bf(hn);
        unsigned pair = (unsigned)hb16 | (__shfl_xor((unsigned)hb16, 1) << 16);
        if ((jj & 1) == 0)
          st_pair_agent((unsigned*)(hdst + row * 1024 + hb) + (jj >> 1), pair);
      }
    }
    if (p < 512) {
      bar_arrive(gcnt, root, (unsigned)(p + 2));
      // private out-stores overlap the spin (nobody reads these in-kernel)
      if (active && layer) out[(size_t)t * 32768 + row * 1024 + col] = hn;
      if (active && t == 511) {
        out[16777216 + layer * 32768 + row * 1024 + col] = hn;   // h_fin
        out[16842752 + layer * 32768 + row * 1024 + col] = cn;   // c_fin
      }
      bar_wait(root, (unsigned)(p + 2));
    } else {
      if (active && layer) out[(size_t)t * 32768 + row * 1024 + col] = hn;
      if (active && t == 511) {
        out[16777216 + layer * 32768 + row * 1024 + col] = hn;
        out[16842752 + layer * 32768 + row * 1024 + col] = cn;
      }
    }
  }
}

extern "C" void kernel_launch(void* const* d_in, const int* in_sizes, int n_in,
                              void* d_out, int out_size, void* d_ws, size_t ws_size,
                              hipStream_t stream)
{
  (void)in_sizes; (void)n_in; (void)out_size; (void)ws_size;
  const float* x  = (const float*)d_in[0];
  const float* h0 = (const float*)d_in[1];
  const float* c0 = (const float*)d_in[2];
  const float* W  = (const float*)d_in[3];
  const float* b  = (const float*)d_in[4];
  float* out = (float*)d_out;

  char* ws = (char*)d_ws;
  u16x8*          xbf_v = (u16x8*)ws;                         //   0       : 32 MB
  u16x8*          wp_v  = (u16x8*)(ws + 33554432);            //  32 MB    : 32 MB
  unsigned short* h1x   = (unsigned short*)(ws + 67108864);   //  64 MB    : 513*64 KB
  unsigned short* h2x   = (unsigned short*)(ws + 100728832);  //  ~96 MB   : 513*64 KB
  unsigned*       gcnt  = (unsigned*)(ws + 134348800);        // 16 x 128 B
  unsigned*       root  = (unsigned*)(ws + 134350848);        // 128 B
  // total ~134.4 MB of ws

  hipMemsetAsync(gcnt, 0, 4096, stream);                      // gcnt + root
  k_conv_x<<<8192, 256, 0, stream>>>(x, xbf_v);
  k_pack_w<<<8192, 256, 0, stream>>>(W, wp_v);

  size_t shmem = 131072 + 18432 + 1024;   // 150528 B < 160 KiB
  hipFuncSetAttribute((const void*)lstm_coop,
                      hipFuncAttributeMaxDynamicSharedMemorySize, (int)(160 * 1024));

  const unsigned short* xbf_p = (const unsigned short*)xbf_v;
  const uint4*          wp_p  = (const uint4*)wp_v;
  void* args[] = {
    (void*)&xbf_p, (void*)&wp_p, (void*)&h0, (void*)&c0, (void*)&b,
    (void*)&h1x, (void*)&h2x, (void*)&out, (void*)&gcnt, (void*)&root
  };
  hipLaunchCooperativeKernel((const void*)lstm_coop, dim3(256), dim3(256),
                             args, (unsigned)shmem, stream);
}